// Round 5
// baseline (383.207 us; speedup 1.0000x reference)
//
#include <hip/hip_runtime.h>
#include <cstdint>

#define B_ 2
#define N_ 50000
#define D_ 128
#define E_ 800000
#define TOK 100000   // B_*N_

typedef __bf16 bf16x8 __attribute__((ext_vector_type(8)));
typedef float f32x4 __attribute__((ext_vector_type(4)));

__device__ __forceinline__ unsigned short f2bf(float f) {
  union { float f; uint32_t u; } v; v.f = f;
  uint32_t u = v.u;
  return (unsigned short)((u + 0x7FFFu + ((u >> 16) & 1u)) >> 16);
}
__device__ __forceinline__ float uasf(uint32_t u) {
  union { uint32_t u; float f; } v; v.u = u; return v.f;
}
// tanh-form GELU: v * sigmoid(1.5958*(v + 0.044715 v^3)); max |err| vs exact
// erf-GELU ~3e-4 << bf16 rounding of h1. Branch-free saturation.
__device__ __forceinline__ float fast_gelu(float v) {
  float p = v * (1.5957691f + 0.07135481f * v * v);
  return v * __builtin_amdgcn_rcpf(1.0f + __expf(-p));
}

// ---- fused prep: xb build (blocks 0..12499), W transpose (12500..12883),
// ---- dst histogram (12884..16008) ------------------------------------------
// W1t/W2t stored FRAGMENT-MAJOR: 16(n)x32(k) tiles, within a tile element
// (n,k) sits at lane=(n&15)+16*((k>>3)&3), j=k&7 -> a wave b-frag load is
// uniform_base + lane*16B (one coalesced 1KB transaction).
__global__ __launch_bounds__(256) void prep_k(
    const float* __restrict__ x, const float* __restrict__ W1,
    const float* __restrict__ W2, const int* __restrict__ edst,
    unsigned short* __restrict__ xb, unsigned short* __restrict__ W1t,
    unsigned short* __restrict__ W2t, int* __restrict__ cnt) {
  const int blk = blockIdx.x;
  if (blk < 12500) {               // x -> batch-interleaved bf16 xb[node][2][128]
    int q = (blk * 256 + threadIdx.x) * 4;
    int node = q >> 8;
    int rem = q & 255;
    int b = rem >> 7, c = rem & 127;
    float4 v = *(const float4*)(x + (size_t)b * (N_ * D_) + node * 128 + c);
    uint2 p = { (uint32_t)f2bf(v.x) | ((uint32_t)f2bf(v.y) << 16),
                (uint32_t)f2bf(v.z) | ((uint32_t)f2bf(v.w) << 16) };
    *(uint2*)(xb + q) = p;
  } else if (blk < 12884) {        // weight transpose -> fragment-major bf16
    int t = (blk - 12500) * 256 + threadIdx.x;
    if (t < 65536) {
      int n = t >> 8, k = t & 255;
      int f = (n >> 4) * 8 + (k >> 5);
      int pos = ((n & 15) + ((k >> 3) & 3) * 16) * 8 + (k & 7);
      W1t[f * 512 + pos] = f2bf(W1[k * 256 + n]);
    } else {
      int t2 = t - 65536;
      int n = t2 >> 8, k = t2 & 255;
      int f = (n >> 4) * 8 + (k >> 5);
      int pos = ((n & 15) + ((k >> 3) & 3) * 16) * 8 + (k & 7);
      W2t[f * 512 + pos] = f2bf(W2[k * 128 + n]);
    }
  } else {                         // histogram of edge_dst
    int e = (blk - 12884) * 256 + threadIdx.x;
    if (e < E_) atomicAdd(&cnt[edst[e]], 1);
  }
}

// ---------------- single-kernel exclusive scan over cnt -> rs, cursor -------
// One workgroup (1024 thr), 13 chunks of 4096 (int4/thread), ping-pong carry.
// Replaces scan1+scan2+scan3 (saves 2 launches).
__global__ __launch_bounds__(1024) void scan_all_k(const int* __restrict__ cnt,
                                                   int* __restrict__ rs,
                                                   int* __restrict__ cursor) {
  __shared__ int wsum[16], woff[16], carry[2];
  const int tid = threadIdx.x, lane = tid & 63, wv = tid >> 6;
  if (tid == 0) carry[0] = 0;
  int p = 0;
  __syncthreads();
  for (int base = 0; base < N_; base += 4096) {
    int i = base + tid * 4;
    int4 v = {0, 0, 0, 0};
    if (i + 3 < N_) {
      v = *(const int4*)(cnt + i);
    } else {
      if (i     < N_) v.x = cnt[i];
      if (i + 1 < N_) v.y = cnt[i + 1];
      if (i + 2 < N_) v.z = cnt[i + 2];
      if (i + 3 < N_) v.w = cnt[i + 3];
    }
    int s4 = v.x + v.y + v.z + v.w;
    int s = s4;
#pragma unroll
    for (int off = 1; off < 64; off <<= 1) {
      int t = __shfl_up(s, off);
      if (lane >= off) s += t;
    }
    if (lane == 63) wsum[wv] = s;
    __syncthreads();
    if (tid == 0) {
      int a = 0;
#pragma unroll
      for (int w = 0; w < 16; ++w) { woff[w] = a; a += wsum[w]; }
      carry[p ^ 1] = carry[p] + a;
    }
    __syncthreads();
    int pre = carry[p] + woff[wv] + (s - s4);   // exclusive prefix of thread's 4
    int e0 = pre, e1 = pre + v.x, e2 = e1 + v.y, e3 = e2 + v.z;
    if (i + 3 < N_) {
      int4 w0 = {e0, e1, e2, e3};
      *(int4*)(rs + i) = w0;
      *(int4*)(cursor + i) = w0;
    } else {
      if (i     < N_) { rs[i]     = e0; cursor[i]     = e0; }
      if (i + 1 < N_) { rs[i + 1] = e1; cursor[i + 1] = e1; }
      if (i + 2 < N_) { rs[i + 2] = e2; cursor[i + 2] = e2; }
      if (i + 3 < N_) { rs[i + 3] = e3; cursor[i + 3] = e3; }
    }
    p ^= 1;
  }
  if (tid == 0) rs[N_] = E_;
}

// ---------------- CSR build: counting-sort edge srcs by dst -----------------
__global__ __launch_bounds__(256) void fill_k(const int* __restrict__ esrc,
                                              const int* __restrict__ edst,
                                              int* __restrict__ cursor,
                                              int* __restrict__ sorted_src) {
  int e = blockIdx.x * 256 + threadIdx.x;
  if (e < E_) {
    int pos = atomicAdd(&cursor[edst[e]], 1);
    sorted_src[pos] = esrc[e];
  }
}

// ---------------- fused gather + dual LayerNorm -> h = [LN(x), LN(nb)] -----
// One wave per node. 32 lanes cover the full 512B row (uint4/lane), the two
// 32-lane halves (g=0/1) process 2 edges in parallel -> 8x16B loads in flight
// per lane.
__global__ __launch_bounds__(256) void gather_ln_k(
    const unsigned short* __restrict__ xb,
    const int* __restrict__ rs, const int* __restrict__ ss,
    const float* __restrict__ sn_g, const float* __restrict__ sn_b,
    const float* __restrict__ nn_g, const float* __restrict__ nn_b,
    unsigned short* __restrict__ h) {
  const int node = blockIdx.x * 4 + (threadIdx.x >> 6);
  const int lane = threadIdx.x & 63;
  const int g = lane >> 5;          // edge-parallel subgroup
  const int l32 = lane & 31;        // 16B chunk within the 512B row
  const int r0 = rs[node], r1 = rs[node + 1];
  const unsigned short* xrow = xb + l32 * 8;   // 8 bf16 per lane
  float acc[8] = {0.f, 0.f, 0.f, 0.f, 0.f, 0.f, 0.f, 0.f};
  for (int e = r0; e < r1; e += 16) {
    int idx[8];
#pragma unroll
    for (int j = 0; j < 8; ++j) {
      int ej = e + 2 * j + g;
      idx[j] = ss[(ej < r1) ? ej : r0];
    }
    uint4 v[8];
#pragma unroll
    for (int j = 0; j < 8; ++j)
      v[j] = *(const uint4*)(xrow + (size_t)idx[j] * 256);
#pragma unroll
    for (int j = 0; j < 8; ++j) {
      if (e + 2 * j + g < r1) {
        acc[0] += uasf(v[j].x << 16); acc[1] += uasf(v[j].x & 0xffff0000u);
        acc[2] += uasf(v[j].y << 16); acc[3] += uasf(v[j].y & 0xffff0000u);
        acc[4] += uasf(v[j].z << 16); acc[5] += uasf(v[j].z & 0xffff0000u);
        acc[6] += uasf(v[j].w << 16); acc[7] += uasf(v[j].w & 0xffff0000u);
      }
    }
  }
  // combine the two edge-parallel halves
#pragma unroll
  for (int k = 0; k < 8; ++k) acc[k] += __shfl_xor(acc[k], 32);
  const float invd = 1.0f / fmaxf((float)(r1 - r0), 1.0f);
  float nb[8];
#pragma unroll
  for (int k = 0; k < 8; ++k) nb[k] = acc[k] * invd;
  uint4 xq = *(const uint4*)(xrow + (size_t)node * 256);  // own row (bf16)
  float xv[8];
  xv[0] = uasf(xq.x << 16); xv[1] = uasf(xq.x & 0xffff0000u);
  xv[2] = uasf(xq.y << 16); xv[3] = uasf(xq.y & 0xffff0000u);
  xv[4] = uasf(xq.z << 16); xv[5] = uasf(xq.z & 0xffff0000u);
  xv[6] = uasf(xq.w << 16); xv[7] = uasf(xq.w & 0xffff0000u);
  float sx = 0.f, sxx = 0.f, sn = 0.f, snn = 0.f;
#pragma unroll
  for (int k = 0; k < 8; ++k) {
    sx += xv[k]; sxx += xv[k] * xv[k];
    sn += nb[k]; snn += nb[k] * nb[k];
  }
  // reduce within the 16-lane batch group (lanes [0,16) b0, [16,32) b1, etc.)
#pragma unroll
  for (int off = 1; off < 16; off <<= 1) {
    sx  += __shfl_xor(sx, off);  sxx += __shfl_xor(sxx, off);
    sn  += __shfl_xor(sn, off);  snn += __shfl_xor(snn, off);
  }
  const float r = 1.0f / 128.0f;
  float mx = sx * r, vx = fmaxf(sxx * r - mx * mx, 0.f);
  float mn = sn * r, vn = fmaxf(snn * r - mn * mn, 0.f);
  float rx = rsqrtf(vx + 1e-5f), rn = rsqrtf(vn + 1e-5f);
  const int c = (l32 & 15) * 8;
  // g==0 lanes write y = LN(x); g==1 lanes write z = LN(nb)
  const float* gp = g ? nn_g : sn_g;
  const float* bp = g ? nn_b : sn_b;
  float4 g0 = *(const float4*)(gp + c), g1 = *(const float4*)(gp + c + 4);
  float4 b0 = *(const float4*)(bp + c), b1v = *(const float4*)(bp + c + 4);
  float gw[8] = {g0.x, g0.y, g0.z, g0.w, g1.x, g1.y, g1.z, g1.w};
  float bw[8] = {b0.x, b0.y, b0.z, b0.w, b1v.x, b1v.y, b1v.z, b1v.w};
  float mu = g ? mn : mx;
  float rs_ = g ? rn : rx;
  float o[8];
#pragma unroll
  for (int k = 0; k < 8; ++k) {
    float s = g ? nb[k] : xv[k];
    o[k] = (s - mu) * rs_ * gw[k] + bw[k];
  }
  uint4 po;
  po.x = (uint32_t)f2bf(o[0]) | ((uint32_t)f2bf(o[1]) << 16);
  po.y = (uint32_t)f2bf(o[2]) | ((uint32_t)f2bf(o[3]) << 16);
  po.z = (uint32_t)f2bf(o[4]) | ((uint32_t)f2bf(o[5]) << 16);
  po.w = (uint32_t)f2bf(o[6]) | ((uint32_t)f2bf(o[7]) << 16);
  unsigned short* hr = h + ((size_t)(l32 >> 4) * N_ + node) * 256 + g * 128 + c;
  *(uint4*)hr = po;
}

// ---------------- fused MLP: out = GELU(h @ W1^T + b1) @ W2^T + b2 + x ------
// v5: BARRIER-FREE. A-rows and Hc-rows are wave-private in this dataflow, so
// waves run fully desynchronized: A-frags straight from global (wave's 16KB
// strip goes L1/L2-hot across the 8 nc chunks), GELU strip in 2KB of
// wave-private LDS (16B-group XOR swizzle, same-wave lgkmcnt fences only).
// 256 thr / 4 waves per 128 rows; acc1[2][2]+acc2[2][8] = 80 acc regs;
// launch_bounds(256,4) -> 16 free-running waves/CU, LDS 8KB/block.
__global__ __launch_bounds__(256, 4) void fused_mlp_k(
    const unsigned short* __restrict__ A,      // h [M][256] bf16
    const unsigned short* __restrict__ W1t,    // frag-major [16x8 tiles][512]
    const unsigned short* __restrict__ W2t,    // frag-major [8x8 tiles][512]
    const float* __restrict__ b1,
    const float* __restrict__ b2,
    const float* __restrict__ resid,           // x fp32 [M][128]
    float* __restrict__ outp, int M) {
  __shared__ unsigned short Hc[4][32][32];     // 8KB, per-wave strips
  const int tid = threadIdx.x;
  const int wv = tid >> 6, lane = tid & 63;
  const int quad = lane >> 4, l15 = lane & 15;
  const int rowbase = blockIdx.x * 128 + wv * 32;
  f32x4 acc2[2][8] = {};
  for (int nc = 0; nc < 8; ++nc) {             // 32-col chunks of h1
    // ---- gemm1 chunk: 32 rows x 32 h1-cols, full K=256, A from global ----
    f32x4 acc1[2][2] = {};
#pragma unroll
    for (int kc = 0; kc < 256; kc += 32) {
      bf16x8 a[2], b[2];
#pragma unroll
      for (int i = 0; i < 2; ++i) {
        int row = rowbase + i * 16 + l15;      // rows >= M read workspace slack (safe, discarded)
        a[i] = *(const bf16x8*)(A + (size_t)row * 256 + kc + quad * 8);
      }
#pragma unroll
      for (int i = 0; i < 2; ++i) {
        int ftile = (nc * 2 + i) * 8 + (kc >> 5);
        b[i] = *(const bf16x8*)(W1t + ftile * 512 + lane * 8);
      }
#pragma unroll
      for (int mi = 0; mi < 2; ++mi)
#pragma unroll
        for (int ni = 0; ni < 2; ++ni)
          acc1[mi][ni] = __builtin_amdgcn_mfma_f32_16x16x32_bf16(a[mi], b[ni], acc1[mi][ni], 0, 0, 0);
    }
    // ---- GELU(acc1+b1) -> wave-private Hc strip (group-XOR swizzled) ----
    // prior gemm2 reads of this strip were consumed by MFMA already; fence anyway
    asm volatile("s_waitcnt lgkmcnt(0)" ::: "memory");
#pragma unroll
    for (int mi = 0; mi < 2; ++mi)
#pragma unroll
      for (int ni = 0; ni < 2; ++ni) {
        int col = ni * 16 + l15;
        float bv = b1[nc * 32 + col];
#pragma unroll
        for (int rr = 0; rr < 4; ++rr) {
          int row = mi * 16 + quad * 4 + rr;
          Hc[wv][row][col ^ ((row & 3) << 3)] = f2bf(fast_gelu(acc1[mi][ni][rr] + bv));
        }
      }
    asm volatile("s_waitcnt lgkmcnt(0)" ::: "memory");  // writes visible to our reads
    // ---- gemm2 partial: acc2 += Hc(32x32) @ W2[:, nc*32..+32] ----
    bf16x8 a2[2], bw2[8];
#pragma unroll
    for (int i = 0; i < 2; ++i) {
      int row = i * 16 + l15;
      a2[i] = *(const bf16x8*)(&Hc[wv][row][(quad * 8) ^ ((row & 3) << 3)]);
    }
#pragma unroll
    for (int i = 0; i < 8; ++i) {
      int ftile = i * 8 + nc;
      bw2[i] = *(const bf16x8*)(W2t + ftile * 512 + lane * 8);
    }
#pragma unroll
    for (int mi = 0; mi < 2; ++mi)
#pragma unroll
      for (int ni = 0; ni < 8; ++ni)
        acc2[mi][ni] = __builtin_amdgcn_mfma_f32_16x16x32_bf16(a2[mi], bw2[ni], acc2[mi][ni], 0, 0, 0);
  }
  // ---- epilogue: + b2 + resid, fp32 out ----
#pragma unroll
  for (int mi = 0; mi < 2; ++mi)
#pragma unroll
    for (int ni = 0; ni < 8; ++ni) {
      int col = ni * 16 + l15;
      float bv = b2[col];
#pragma unroll
      for (int rr = 0; rr < 4; ++rr) {
        int row = rowbase + mi * 16 + quad * 4 + rr;
        if (row < M) {
          float v = acc2[mi][ni][rr] + bv + resid[(size_t)row * 128 + col];
          outp[(size_t)row * 128 + col] = v;
        }
      }
    }
}

extern "C" void kernel_launch(void* const* d_in, const int* in_sizes, int n_in,
                              void* d_out, int out_size, void* d_ws, size_t ws_size,
                              hipStream_t stream) {
  const float* x    = (const float*)d_in[0];
  const int* esrc   = (const int*)d_in[1];
  const int* edst   = (const int*)d_in[2];
  const float* sn_g = (const float*)d_in[4];
  const float* sn_b = (const float*)d_in[5];
  const float* nn_g = (const float*)d_in[6];
  const float* nn_b = (const float*)d_in[7];
  const float* W1   = (const float*)d_in[8];
  const float* b1   = (const float*)d_in[9];
  const float* W2   = (const float*)d_in[10];
  const float* b2   = (const float*)d_in[11];

  char* ws = (char*)d_ws;
  const size_t H_BYTES = (size_t)TOK * 256 * 2;          // 51.2 MB
  unsigned short* h = (unsigned short*)ws;               // [TOK][256] bf16
  // CSR + xb region (dead after gather):
  char* csr = ws + H_BYTES;
  int* cnt        = (int*)(csr);                          // 50000 ints
  int* rs         = (int*)(csr + 400000);                 // 50001 ints
  int* cursor     = (int*)(csr + 600016);                 // 50000 ints
  int* sorted_src = (int*)(csr + 800512);                 // 800000 ints -> ends 4,000,512
  unsigned short* xb = (unsigned short*)(csr + 4194304);  // [N][2][128] bf16, 25.6 MB
  unsigned short* W1t = (unsigned short*)(ws + 2 * H_BYTES);
  unsigned short* W2t = W1t + 65536;

  hipMemsetAsync(cnt, 0, (size_t)N_ * sizeof(int), stream);
  prep_k<<<16009, 256, 0, stream>>>(x, W1, W2, edst, xb, W1t, W2t, cnt);
  scan_all_k<<<1, 1024, 0, stream>>>(cnt, rs, cursor);
  fill_k<<<(E_ + 255) / 256, 256, 0, stream>>>(esrc, edst, cursor, sorted_src);
  gather_ln_k<<<N_ / 4, 256, 0, stream>>>(xb, rs, sorted_src,
                                          sn_g, sn_b, nn_g, nn_b, h);
  fused_mlp_k<<<(TOK + 127) / 128, 256, 0, stream>>>(h, W1t, W2t, b1, b2,
                                                     x, (float*)d_out, TOK);
}

// Round 6
// 344.805 us; speedup vs baseline: 1.1114x; 1.1114x over previous
//
#include <hip/hip_runtime.h>
#include <cstdint>

#define B_ 2
#define N_ 50000
#define D_ 128
#define E_ 800000
#define TOK 100000   // B_*N_

typedef __bf16 bf16x8 __attribute__((ext_vector_type(8)));
typedef float f32x4 __attribute__((ext_vector_type(4)));

__device__ __forceinline__ unsigned short f2bf(float f) {
  union { float f; uint32_t u; } v; v.f = f;
  uint32_t u = v.u;
  return (unsigned short)((u + 0x7FFFu + ((u >> 16) & 1u)) >> 16);
}
__device__ __forceinline__ float uasf(uint32_t u) {
  union { uint32_t u; float f; } v; v.u = u; return v.f;
}
// tanh-form GELU: v * sigmoid(1.5958*(v + 0.044715 v^3)); max |err| vs exact
// erf-GELU ~3e-4 << bf16 rounding of h1. Branch-free saturation.
__device__ __forceinline__ float fast_gelu(float v) {
  float p = v * (1.5957691f + 0.07135481f * v * v);
  return v * __builtin_amdgcn_rcpf(1.0f + __expf(-p));
}

// ---- fused prep: xb build (blocks 0..12499), W transpose (12500..12883),
// ---- dst histogram (12884..16008) ------------------------------------------
// W1t/W2t stored FRAGMENT-MAJOR: 16(n)x32(k) tiles, within a tile element
// (n,k) sits at lane=(n&15)+16*((k>>3)&3), j=k&7 -> a wave b-frag load is
// uniform_base + lane*16B (one coalesced 1KB transaction).
__global__ __launch_bounds__(256) void prep_k(
    const float* __restrict__ x, const float* __restrict__ W1,
    const float* __restrict__ W2, const int* __restrict__ edst,
    unsigned short* __restrict__ xb, unsigned short* __restrict__ W1t,
    unsigned short* __restrict__ W2t, int* __restrict__ cnt) {
  const int blk = blockIdx.x;
  if (blk < 12500) {               // x -> batch-interleaved bf16 xb[node][2][128]
    int q = (blk * 256 + threadIdx.x) * 4;
    int node = q >> 8;
    int rem = q & 255;
    int b = rem >> 7, c = rem & 127;
    float4 v = *(const float4*)(x + (size_t)b * (N_ * D_) + node * 128 + c);
    uint2 p = { (uint32_t)f2bf(v.x) | ((uint32_t)f2bf(v.y) << 16),
                (uint32_t)f2bf(v.z) | ((uint32_t)f2bf(v.w) << 16) };
    *(uint2*)(xb + q) = p;
  } else if (blk < 12884) {        // weight transpose -> fragment-major bf16
    int t = (blk - 12500) * 256 + threadIdx.x;
    if (t < 65536) {
      int n = t >> 8, k = t & 255;
      int f = (n >> 4) * 8 + (k >> 5);
      int pos = ((n & 15) + ((k >> 3) & 3) * 16) * 8 + (k & 7);
      W1t[f * 512 + pos] = f2bf(W1[k * 256 + n]);
    } else {
      int t2 = t - 65536;
      int n = t2 >> 8, k = t2 & 255;
      int f = (n >> 4) * 8 + (k >> 5);
      int pos = ((n & 15) + ((k >> 3) & 3) * 16) * 8 + (k & 7);
      W2t[f * 512 + pos] = f2bf(W2[k * 128 + n]);
    }
  } else {                         // histogram of edge_dst
    int e = (blk - 12884) * 256 + threadIdx.x;
    if (e < E_) atomicAdd(&cnt[edst[e]], 1);
  }
}

// ---------------- single-kernel exclusive scan over cnt -> rs, cursor -------
// One workgroup (1024 thr), 13 chunks of 4096 (int4/thread), ping-pong carry.
__global__ __launch_bounds__(1024) void scan_all_k(const int* __restrict__ cnt,
                                                   int* __restrict__ rs,
                                                   int* __restrict__ cursor) {
  __shared__ int wsum[16], woff[16], carry[2];
  const int tid = threadIdx.x, lane = tid & 63, wv = tid >> 6;
  if (tid == 0) carry[0] = 0;
  int p = 0;
  __syncthreads();
  for (int base = 0; base < N_; base += 4096) {
    int i = base + tid * 4;
    int4 v = {0, 0, 0, 0};
    if (i + 3 < N_) {
      v = *(const int4*)(cnt + i);
    } else {
      if (i     < N_) v.x = cnt[i];
      if (i + 1 < N_) v.y = cnt[i + 1];
      if (i + 2 < N_) v.z = cnt[i + 2];
      if (i + 3 < N_) v.w = cnt[i + 3];
    }
    int s4 = v.x + v.y + v.z + v.w;
    int s = s4;
#pragma unroll
    for (int off = 1; off < 64; off <<= 1) {
      int t = __shfl_up(s, off);
      if (lane >= off) s += t;
    }
    if (lane == 63) wsum[wv] = s;
    __syncthreads();
    if (tid == 0) {
      int a = 0;
#pragma unroll
      for (int w = 0; w < 16; ++w) { woff[w] = a; a += wsum[w]; }
      carry[p ^ 1] = carry[p] + a;
    }
    __syncthreads();
    int pre = carry[p] + woff[wv] + (s - s4);   // exclusive prefix of thread's 4
    int e0 = pre, e1 = pre + v.x, e2 = e1 + v.y, e3 = e2 + v.z;
    if (i + 3 < N_) {
      int4 w0 = {e0, e1, e2, e3};
      *(int4*)(rs + i) = w0;
      *(int4*)(cursor + i) = w0;
    } else {
      if (i     < N_) { rs[i]     = e0; cursor[i]     = e0; }
      if (i + 1 < N_) { rs[i + 1] = e1; cursor[i + 1] = e1; }
      if (i + 2 < N_) { rs[i + 2] = e2; cursor[i + 2] = e2; }
      if (i + 3 < N_) { rs[i + 3] = e3; cursor[i + 3] = e3; }
    }
    p ^= 1;
  }
  if (tid == 0) rs[N_] = E_;
}

// ---------------- CSR build: counting-sort edge srcs by dst -----------------
__global__ __launch_bounds__(256) void fill_k(const int* __restrict__ esrc,
                                              const int* __restrict__ edst,
                                              int* __restrict__ cursor,
                                              int* __restrict__ sorted_src) {
  int e = blockIdx.x * 256 + threadIdx.x;
  if (e < E_) {
    int pos = atomicAdd(&cursor[edst[e]], 1);
    sorted_src[pos] = esrc[e];
  }
}

// ============ fused gather + dual-LN + MLP + residual (one kernel) ==========
// Block = 64 nodes (128 token rows, order node_local*2+b), 512 thr / 8 waves.
// Phase 1 (gather): wave wv gathers nodes bn0+wv*8 .. +7 sequentially with the
// verified gather_ln body; LN output written DIRECTLY into the swizzled As
// tile (same XOR layout v4's gemm1 reads). Kills the 100MB h round-trip.
// Phase 2 (MLP): v4's verified 8-wave MLP (As staged once, Hc 16KB, frag-major
// W from global/L2). Epilogue remaps local row -> token (b*N+node).
// LDS 64K+16K=80KB -> 2 blocks/CU = 16 waves/CU; gather of one block overlaps
// the MFMA phase of the co-resident block.
__global__ __launch_bounds__(512, 2) void gather_mlp_k(
    const unsigned short* __restrict__ xb,
    const int* __restrict__ rs, const int* __restrict__ ss,
    const float* __restrict__ sn_g, const float* __restrict__ sn_b,
    const float* __restrict__ nn_g, const float* __restrict__ nn_b,
    const unsigned short* __restrict__ W1t,    // frag-major [16x8 tiles][512]
    const unsigned short* __restrict__ W2t,    // frag-major [8x8 tiles][512]
    const float* __restrict__ b1,
    const float* __restrict__ b2,
    const float* __restrict__ resid,           // x fp32 [B][N][128]
    float* __restrict__ outp) {
  __shared__ unsigned short As[128 * 256];   // 64KB, swizzled: chunk ^ (row&7)
  __shared__ unsigned short Hc[128 * 64];    // 16KB, swizzled: elem ^ ((row&7)<<3)
  const int tid = threadIdx.x;
  const int wave = tid >> 6, lane = tid & 63;
  const int g = lane >> 5;          // edge-parallel subgroup
  const int l32 = lane & 31;        // 16B chunk within the 512B xb row
  const int bn0 = blockIdx.x * 64;
  const unsigned short* xrow = xb + l32 * 8;

  // ---------------- phase 1: gather + dual LN -> As (LDS) ----------------
  for (int t = 0; t < 8; ++t) {
    const int node = bn0 + wave * 8 + t;
    if (node < N_) {
      const int r0 = rs[node], r1 = rs[node + 1];
      float acc[8] = {0.f, 0.f, 0.f, 0.f, 0.f, 0.f, 0.f, 0.f};
      for (int e = r0; e < r1; e += 16) {
        int idx[8];
#pragma unroll
        for (int j = 0; j < 8; ++j) {
          int ej = e + 2 * j + g;
          idx[j] = ss[(ej < r1) ? ej : r0];
        }
        uint4 v[8];
#pragma unroll
        for (int j = 0; j < 8; ++j)
          v[j] = *(const uint4*)(xrow + (size_t)idx[j] * 256);
#pragma unroll
        for (int j = 0; j < 8; ++j) {
          if (e + 2 * j + g < r1) {
            acc[0] += uasf(v[j].x << 16); acc[1] += uasf(v[j].x & 0xffff0000u);
            acc[2] += uasf(v[j].y << 16); acc[3] += uasf(v[j].y & 0xffff0000u);
            acc[4] += uasf(v[j].z << 16); acc[5] += uasf(v[j].z & 0xffff0000u);
            acc[6] += uasf(v[j].w << 16); acc[7] += uasf(v[j].w & 0xffff0000u);
          }
        }
      }
#pragma unroll
      for (int k = 0; k < 8; ++k) acc[k] += __shfl_xor(acc[k], 32);
      const float invd = 1.0f / fmaxf((float)(r1 - r0), 1.0f);
      float nb[8];
#pragma unroll
      for (int k = 0; k < 8; ++k) nb[k] = acc[k] * invd;
      uint4 xq = *(const uint4*)(xrow + (size_t)node * 256);  // own row (bf16)
      float xv[8];
      xv[0] = uasf(xq.x << 16); xv[1] = uasf(xq.x & 0xffff0000u);
      xv[2] = uasf(xq.y << 16); xv[3] = uasf(xq.y & 0xffff0000u);
      xv[4] = uasf(xq.z << 16); xv[5] = uasf(xq.z & 0xffff0000u);
      xv[6] = uasf(xq.w << 16); xv[7] = uasf(xq.w & 0xffff0000u);
      float sx = 0.f, sxx = 0.f, sn = 0.f, snn = 0.f;
#pragma unroll
      for (int k = 0; k < 8; ++k) {
        sx += xv[k]; sxx += xv[k] * xv[k];
        sn += nb[k]; snn += nb[k] * nb[k];
      }
      // reduce within 16-lane subgroup (each subgroup = one batch's 128 cols)
#pragma unroll
      for (int off = 1; off < 16; off <<= 1) {
        sx  += __shfl_xor(sx, off);  sxx += __shfl_xor(sxx, off);
        sn  += __shfl_xor(sn, off);  snn += __shfl_xor(snn, off);
      }
      const float r = 1.0f / 128.0f;
      float mx = sx * r, vx = fmaxf(sxx * r - mx * mx, 0.f);
      float mn = sn * r, vn = fmaxf(snn * r - mn * mn, 0.f);
      float rx = rsqrtf(vx + 1e-5f), rn = rsqrtf(vn + 1e-5f);
      const int c = (l32 & 15) * 8;
      // g==0 lanes write y = LN(x) (cols 0..127); g==1 write z = LN(nb) (128..255)
      const float* gp = g ? nn_g : sn_g;
      const float* bp = g ? nn_b : sn_b;
      float4 g0 = *(const float4*)(gp + c), g1 = *(const float4*)(gp + c + 4);
      float4 b0 = *(const float4*)(bp + c), b1v = *(const float4*)(bp + c + 4);
      float gw[8] = {g0.x, g0.y, g0.z, g0.w, g1.x, g1.y, g1.z, g1.w};
      float bw[8] = {b0.x, b0.y, b0.z, b0.w, b1v.x, b1v.y, b1v.z, b1v.w};
      float mu = g ? mn : mx;
      float rs_ = g ? rn : rx;
      float o[8];
#pragma unroll
      for (int k = 0; k < 8; ++k) {
        float s = g ? nb[k] : xv[k];
        o[k] = (s - mu) * rs_ * gw[k] + bw[k];
      }
      uint4 po;
      po.x = (uint32_t)f2bf(o[0]) | ((uint32_t)f2bf(o[1]) << 16);
      po.y = (uint32_t)f2bf(o[2]) | ((uint32_t)f2bf(o[3]) << 16);
      po.z = (uint32_t)f2bf(o[4]) | ((uint32_t)f2bf(o[5]) << 16);
      po.w = (uint32_t)f2bf(o[6]) | ((uint32_t)f2bf(o[7]) << 16);
      // local token row r = n_local*2 + batch; 16B chunk c16 = g*16 + (l32&15)
      const int rr_ = (node - bn0) * 2 + (l32 >> 4);
      const int c16 = g * 16 + (l32 & 15);
      *(uint4*)(&As[rr_ * 256 + ((c16 ^ (rr_ & 7)) << 3)]) = po;
    }
  }
  __syncthreads();   // As fully built

  // ---------------- phase 2: MLP (v4 structure, A-staging deleted) --------
  const int wr = wave >> 1;        // 0..3: 32-row strip
  const int wc = wave & 1;         // 0/1: column half
  const int quad = lane >> 4, l15 = lane & 15;
  f32x4 acc2[2][4] = {};
  for (int nc = 0; nc < 4; ++nc) {
    // ---- gemm1 chunk: 128 rows x 64 h1-cols; wave owns 32x32 ----
    f32x4 acc1[2][2] = {};
#pragma unroll
    for (int kc = 0; kc < 256; kc += 32) {
      bf16x8 a[2], b[2];
#pragma unroll
      for (int i = 0; i < 2; ++i) {
        int row = wr * 32 + i * 16 + l15;
        a[i] = *(const bf16x8*)(&As[row * 256 + ((kc + quad * 8) ^ ((row & 7) << 3))]);
      }
#pragma unroll
      for (int i = 0; i < 2; ++i) {
        int ftile = (nc * 4 + wc * 2 + i) * 8 + (kc >> 5);
        b[i] = *(const bf16x8*)(W1t + ftile * 512 + lane * 8);
      }
#pragma unroll
      for (int mi = 0; mi < 2; ++mi)
#pragma unroll
        for (int ni = 0; ni < 2; ++ni)
          acc1[mi][ni] = __builtin_amdgcn_mfma_f32_16x16x32_bf16(a[mi], b[ni], acc1[mi][ni], 0, 0, 0);
    }
    __syncthreads();   // prev iter's gemm2 finished reading Hc
    // ---- GELU(acc1 + b1) -> Hc (bf16, swizzled) ----
#pragma unroll
    for (int mi = 0; mi < 2; ++mi)
#pragma unroll
      for (int ni = 0; ni < 2; ++ni) {
        int col = wc * 32 + ni * 16 + l15;
        float bv = b1[nc * 64 + col];
#pragma unroll
        for (int rr = 0; rr < 4; ++rr) {
          int row = wr * 32 + mi * 16 + quad * 4 + rr;
          Hc[row * 64 + (col ^ ((row & 7) << 3))] = f2bf(fast_gelu(acc1[mi][ni][rr] + bv));
        }
      }
    __syncthreads();
    // ---- gemm2 partial: acc2 += Hc(128x64) @ W2[:, nc*64 .. +64]; 32x64/wave
#pragma unroll
    for (int kc = 0; kc < 64; kc += 32) {
      bf16x8 a[2], b[4];
#pragma unroll
      for (int i = 0; i < 2; ++i) {
        int row = wr * 32 + i * 16 + l15;
        a[i] = *(const bf16x8*)(&Hc[row * 64 + ((kc + quad * 8) ^ ((row & 7) << 3))]);
      }
#pragma unroll
      for (int i = 0; i < 4; ++i) {
        int ftile = (wc * 4 + i) * 8 + nc * 2 + (kc >> 5);
        b[i] = *(const bf16x8*)(W2t + ftile * 512 + lane * 8);
      }
#pragma unroll
      for (int mi = 0; mi < 2; ++mi)
#pragma unroll
        for (int ni = 0; ni < 4; ++ni)
          acc2[mi][ni] = __builtin_amdgcn_mfma_f32_16x16x32_bf16(a[mi], b[ni], acc2[mi][ni], 0, 0, 0);
    }
  }
  // ---- epilogue: + b2 + resid, fp32 out; local row -> token = b*N + node ----
#pragma unroll
  for (int mi = 0; mi < 2; ++mi)
#pragma unroll
    for (int ni = 0; ni < 4; ++ni) {
      int col = wc * 64 + ni * 16 + l15;
      float bv = b2[col];
#pragma unroll
      for (int rr = 0; rr < 4; ++rr) {
        int lr = wr * 32 + mi * 16 + quad * 4 + rr;
        int node = bn0 + (lr >> 1);
        if (node < N_) {
          size_t tok = (size_t)(lr & 1) * N_ + node;
          float v = acc2[mi][ni][rr] + bv + resid[tok * 128 + col];
          outp[tok * 128 + col] = v;
        }
      }
    }
}

extern "C" void kernel_launch(void* const* d_in, const int* in_sizes, int n_in,
                              void* d_out, int out_size, void* d_ws, size_t ws_size,
                              hipStream_t stream) {
  const float* x    = (const float*)d_in[0];
  const int* esrc   = (const int*)d_in[1];
  const int* edst   = (const int*)d_in[2];
  const float* sn_g = (const float*)d_in[4];
  const float* sn_b = (const float*)d_in[5];
  const float* nn_g = (const float*)d_in[6];
  const float* nn_b = (const float*)d_in[7];
  const float* W1   = (const float*)d_in[8];
  const float* b1   = (const float*)d_in[9];
  const float* W2   = (const float*)d_in[10];
  const float* b2   = (const float*)d_in[11];

  char* ws = (char*)d_ws;
  const size_t H_BYTES = (size_t)TOK * 256 * 2;          // 51.2 MB (region kept, h unused now)
  // CSR + xb region:
  char* csr = ws + H_BYTES;
  int* cnt        = (int*)(csr);                          // 50000 ints
  int* rs         = (int*)(csr + 400000);                 // 50001 ints
  int* cursor     = (int*)(csr + 600016);                 // 50000 ints
  int* sorted_src = (int*)(csr + 800512);                 // 800000 ints -> ends 4,000,512
  unsigned short* xb = (unsigned short*)(csr + 4194304);  // [N][2][128] bf16, 25.6 MB
  unsigned short* W1t = (unsigned short*)(ws + 2 * H_BYTES);
  unsigned short* W2t = W1t + 65536;

  hipMemsetAsync(cnt, 0, (size_t)N_ * sizeof(int), stream);
  prep_k<<<16009, 256, 0, stream>>>(x, W1, W2, edst, xb, W1t, W2t, cnt);
  scan_all_k<<<1, 1024, 0, stream>>>(cnt, rs, cursor);
  fill_k<<<(E_ + 255) / 256, 256, 0, stream>>>(esrc, edst, cursor, sorted_src);
  gather_mlp_k<<<(N_ + 63) / 64, 512, 0, stream>>>(xb, rs, sorted_src,
                                                   sn_g, sn_b, nn_g, nn_b,
                                                   W1t, W2t, b1, b2,
                                                   x, (float*)d_out);
}

// Round 7
// 321.978 us; speedup vs baseline: 1.1902x; 1.0709x over previous
//
#include <hip/hip_runtime.h>
#include <cstdint>

#define B_ 2
#define N_ 50000
#define D_ 128
#define E_ 800000
#define TOK 100000   // B_*N_

typedef __bf16 bf16x8 __attribute__((ext_vector_type(8)));
typedef float f32x4 __attribute__((ext_vector_type(4)));

__device__ __forceinline__ unsigned short f2bf(float f) {
  union { float f; uint32_t u; } v; v.f = f;
  uint32_t u = v.u;
  return (unsigned short)((u + 0x7FFFu + ((u >> 16) & 1u)) >> 16);
}
__device__ __forceinline__ float uasf(uint32_t u) {
  union { uint32_t u; float f; } v; v.u = u; return v.f;
}
// tanh-form GELU: v * sigmoid(1.5958*(v + 0.044715 v^3)); max |err| vs exact
// erf-GELU ~3e-4 << bf16 rounding of h1. Branch-free saturation.
__device__ __forceinline__ float fast_gelu(float v) {
  float p = v * (1.5957691f + 0.07135481f * v * v);
  return v * __builtin_amdgcn_rcpf(1.0f + __expf(-p));
}

// ---- fused prep: xb build (blocks 0..12499), W transpose (12500..12883),
// ---- dst histogram (12884..16008) ------------------------------------------
// W1t/W2t stored FRAGMENT-MAJOR: 16(n)x32(k) tiles, within a tile element
// (n,k) sits at lane=(n&15)+16*((k>>3)&3), j=k&7 -> a wave b-frag load is
// uniform_base + lane*16B (one coalesced 1KB transaction).
__global__ __launch_bounds__(256) void prep_k(
    const float* __restrict__ x, const float* __restrict__ W1,
    const float* __restrict__ W2, const int* __restrict__ edst,
    unsigned short* __restrict__ xb, unsigned short* __restrict__ W1t,
    unsigned short* __restrict__ W2t, int* __restrict__ cnt) {
  const int blk = blockIdx.x;
  if (blk < 12500) {               // x -> batch-interleaved bf16 xb[node][2][128]
    int q = (blk * 256 + threadIdx.x) * 4;
    int node = q >> 8;
    int rem = q & 255;
    int b = rem >> 7, c = rem & 127;
    float4 v = *(const float4*)(x + (size_t)b * (N_ * D_) + node * 128 + c);
    uint2 p = { (uint32_t)f2bf(v.x) | ((uint32_t)f2bf(v.y) << 16),
                (uint32_t)f2bf(v.z) | ((uint32_t)f2bf(v.w) << 16) };
    *(uint2*)(xb + q) = p;
  } else if (blk < 12884) {        // weight transpose -> fragment-major bf16
    int t = (blk - 12500) * 256 + threadIdx.x;
    if (t < 65536) {
      int n = t >> 8, k = t & 255;
      int f = (n >> 4) * 8 + (k >> 5);
      int pos = ((n & 15) + ((k >> 3) & 3) * 16) * 8 + (k & 7);
      W1t[f * 512 + pos] = f2bf(W1[k * 256 + n]);
    } else {
      int t2 = t - 65536;
      int n = t2 >> 8, k = t2 & 255;
      int f = (n >> 4) * 8 + (k >> 5);
      int pos = ((n & 15) + ((k >> 3) & 3) * 16) * 8 + (k & 7);
      W2t[f * 512 + pos] = f2bf(W2[k * 128 + n]);
    }
  } else {                         // histogram of edge_dst
    int e = (blk - 12884) * 256 + threadIdx.x;
    if (e < E_) atomicAdd(&cnt[edst[e]], 1);
  }
}

// ---------------- hierarchical scan: phase 1 (block-local) ------------------
__global__ __launch_bounds__(1024) void scan1_k(const int* __restrict__ cnt,
                                                int* __restrict__ part,
                                                int* __restrict__ bsum) {
  __shared__ int wsum[16], woff[16];
  const int tid = threadIdx.x, lane = tid & 63, wv = tid >> 6;
  int i = blockIdx.x * 1024 + tid;
  int v = (i < N_) ? cnt[i] : 0;
  int s = v;
#pragma unroll
  for (int off = 1; off < 64; off <<= 1) {
    int t = __shfl_up(s, off);
    if (lane >= off) s += t;
  }
  if (lane == 63) wsum[wv] = s;
  __syncthreads();
  if (tid == 0) {
    int a = 0;
#pragma unroll
    for (int w = 0; w < 16; ++w) { woff[w] = a; a += wsum[w]; }
    bsum[blockIdx.x] = a;
  }
  __syncthreads();
  if (i < N_) part[i] = woff[wv] + s - v;
}

// ---------------- phase 2: scan the 49 block sums (one wave) ----------------
__global__ __launch_bounds__(64) void scan2_k(const int* __restrict__ bsum,
                                              int* __restrict__ boff) {
  int lane = threadIdx.x;
  int v = (lane < 49) ? bsum[lane] : 0;
  int s = v;
#pragma unroll
  for (int off = 1; off < 64; off <<= 1) {
    int t = __shfl_up(s, off);
    if (lane >= off) s += t;
  }
  boff[lane] = s - v;
}

// ---------------- phase 3: add block offsets, write rs + cursor -------------
__global__ __launch_bounds__(1024) void scan3_k(const int* __restrict__ part,
                                                const int* __restrict__ boff,
                                                int* __restrict__ rs,
                                                int* __restrict__ cursor) {
  int i = blockIdx.x * 1024 + threadIdx.x;
  if (i < N_) {
    int v = part[i] + boff[blockIdx.x];
    rs[i] = v; cursor[i] = v;
  }
  if (i == 0) rs[N_] = E_;
}

// ---------------- CSR build: counting-sort edge srcs by dst -----------------
__global__ __launch_bounds__(256) void fill_k(const int* __restrict__ esrc,
                                              const int* __restrict__ edst,
                                              int* __restrict__ cursor,
                                              int* __restrict__ sorted_src) {
  int e = blockIdx.x * 256 + threadIdx.x;
  if (e < E_) {
    int pos = atomicAdd(&cursor[edst[e]], 1);
    sorted_src[pos] = esrc[e];
  }
}

// ---------------- fused gather + dual LayerNorm -> h = [LN(x), LN(nb)] -----
// One wave per node. 32 lanes cover the full 512B row (uint4/lane), the two
// 32-lane halves (g=0/1) process 2 edges in parallel -> 8x16B loads in flight
// per lane.
__global__ __launch_bounds__(256) void gather_ln_k(
    const unsigned short* __restrict__ xb,
    const int* __restrict__ rs, const int* __restrict__ ss,
    const float* __restrict__ sn_g, const float* __restrict__ sn_b,
    const float* __restrict__ nn_g, const float* __restrict__ nn_b,
    unsigned short* __restrict__ h) {
  const int node = blockIdx.x * 4 + (threadIdx.x >> 6);
  const int lane = threadIdx.x & 63;
  const int g = lane >> 5;          // edge-parallel subgroup
  const int l32 = lane & 31;        // 16B chunk within the 512B row
  const int r0 = rs[node], r1 = rs[node + 1];
  const unsigned short* xrow = xb + l32 * 8;   // 8 bf16 per lane
  float acc[8] = {0.f, 0.f, 0.f, 0.f, 0.f, 0.f, 0.f, 0.f};
  for (int e = r0; e < r1; e += 16) {
    int idx[8];
#pragma unroll
    for (int j = 0; j < 8; ++j) {
      int ej = e + 2 * j + g;
      idx[j] = ss[(ej < r1) ? ej : r0];
    }
    uint4 v[8];
#pragma unroll
    for (int j = 0; j < 8; ++j)
      v[j] = *(const uint4*)(xrow + (size_t)idx[j] * 256);
#pragma unroll
    for (int j = 0; j < 8; ++j) {
      if (e + 2 * j + g < r1) {
        acc[0] += uasf(v[j].x << 16); acc[1] += uasf(v[j].x & 0xffff0000u);
        acc[2] += uasf(v[j].y << 16); acc[3] += uasf(v[j].y & 0xffff0000u);
        acc[4] += uasf(v[j].z << 16); acc[5] += uasf(v[j].z & 0xffff0000u);
        acc[6] += uasf(v[j].w << 16); acc[7] += uasf(v[j].w & 0xffff0000u);
      }
    }
  }
  // combine the two edge-parallel halves
#pragma unroll
  for (int k = 0; k < 8; ++k) acc[k] += __shfl_xor(acc[k], 32);
  const float invd = 1.0f / fmaxf((float)(r1 - r0), 1.0f);
  float nb[8];
#pragma unroll
  for (int k = 0; k < 8; ++k) nb[k] = acc[k] * invd;
  uint4 xq = *(const uint4*)(xrow + (size_t)node * 256);  // own row (bf16)
  float xv[8];
  xv[0] = uasf(xq.x << 16); xv[1] = uasf(xq.x & 0xffff0000u);
  xv[2] = uasf(xq.y << 16); xv[3] = uasf(xq.y & 0xffff0000u);
  xv[4] = uasf(xq.z << 16); xv[5] = uasf(xq.z & 0xffff0000u);
  xv[6] = uasf(xq.w << 16); xv[7] = uasf(xq.w & 0xffff0000u);
  float sx = 0.f, sxx = 0.f, sn = 0.f, snn = 0.f;
#pragma unroll
  for (int k = 0; k < 8; ++k) {
    sx += xv[k]; sxx += xv[k] * xv[k];
    sn += nb[k]; snn += nb[k] * nb[k];
  }
  // reduce within the 16-lane batch group (lanes [0,16) b0, [16,32) b1, etc.)
#pragma unroll
  for (int off = 1; off < 16; off <<= 1) {
    sx  += __shfl_xor(sx, off);  sxx += __shfl_xor(sxx, off);
    sn  += __shfl_xor(sn, off);  snn += __shfl_xor(snn, off);
  }
  const float r = 1.0f / 128.0f;
  float mx = sx * r, vx = fmaxf(sxx * r - mx * mx, 0.f);
  float mn = sn * r, vn = fmaxf(snn * r - mn * mn, 0.f);
  float rx = rsqrtf(vx + 1e-5f), rn = rsqrtf(vn + 1e-5f);
  const int c = (l32 & 15) * 8;
  // g==0 lanes write y = LN(x); g==1 lanes write z = LN(nb)
  const float* gp = g ? nn_g : sn_g;
  const float* bp = g ? nn_b : sn_b;
  float4 g0 = *(const float4*)(gp + c), g1 = *(const float4*)(gp + c + 4);
  float4 b0 = *(const float4*)(bp + c), b1v = *(const float4*)(bp + c + 4);
  float gw[8] = {g0.x, g0.y, g0.z, g0.w, g1.x, g1.y, g1.z, g1.w};
  float bw[8] = {b0.x, b0.y, b0.z, b0.w, b1v.x, b1v.y, b1v.z, b1v.w};
  float mu = g ? mn : mx;
  float rs_ = g ? rn : rx;
  float o[8];
#pragma unroll
  for (int k = 0; k < 8; ++k) {
    float s = g ? nb[k] : xv[k];
    o[k] = (s - mu) * rs_ * gw[k] + bw[k];
  }
  uint4 po;
  po.x = (uint32_t)f2bf(o[0]) | ((uint32_t)f2bf(o[1]) << 16);
  po.y = (uint32_t)f2bf(o[2]) | ((uint32_t)f2bf(o[3]) << 16);
  po.z = (uint32_t)f2bf(o[4]) | ((uint32_t)f2bf(o[5]) << 16);
  po.w = (uint32_t)f2bf(o[6]) | ((uint32_t)f2bf(o[7]) << 16);
  unsigned short* hr = h + ((size_t)(l32 >> 4) * N_ + node) * 256 + g * 128 + c;
  *(uint4*)hr = po;
}

// ---------------- fused MLP: out = GELU(h @ W1^T + b1) @ W2^T + b2 + x ------
// v7: v4 inner code, BM 128 -> 64. As 32KB + Hc 8KB = 40KB -> 4 blocks/CU
// (160KB LDS exact) = 4 INDEPENDENT barrier domains per CU (v4 had 2), same
// 16 waves/CU. One block's barrier drain overlaps three other blocks' work.
// 256 thr / 4 waves; per-wave tile unchanged (32 rows: acc1[2][2]+acc2[2][4]).
__global__ __launch_bounds__(256, 4) void fused_mlp_k(
    const unsigned short* __restrict__ A,      // h [M][256] bf16
    const unsigned short* __restrict__ W1t,    // frag-major [16x8 tiles][512]
    const unsigned short* __restrict__ W2t,    // frag-major [8x8 tiles][512]
    const float* __restrict__ b1,
    const float* __restrict__ b2,
    const float* __restrict__ resid,           // x fp32 [M][128]
    float* __restrict__ outp, int M) {
  __shared__ unsigned short As[64 * 256];    // 32768 B, swizzled: chunk ^ (row&7)
  __shared__ unsigned short Hc[64 * 64];     // 8192 B, swizzled: elem ^ ((row&7)<<3)
  const int tid = threadIdx.x;
  const int wave = tid >> 6, lane = tid & 63;
  const int wr = wave >> 1;        // 0..1: 32-row strip
  const int wc = wave & 1;         // 0/1: column half
  const int quad = lane >> 4, l15 = lane & 15;
  const int m0 = blockIdx.x * 64;
  // ---- stage A tile once: 64 rows x 32 16B-chunks, 8 iters x 256 thr ----
  {
    uint4 v[8];
#pragma unroll
    for (int it = 0; it < 8; ++it) {
      int id = it * 256 + tid;
      int r = id >> 5, c16 = id & 31;
      int gm = m0 + r;
      uint4 va = {0u, 0u, 0u, 0u};
      if (gm < M) va = *(const uint4*)(A + (size_t)gm * 256 + c16 * 8);
      v[it] = va;
    }
#pragma unroll
    for (int it = 0; it < 8; ++it) {
      int id = it * 256 + tid;
      int r = id >> 5, c16 = id & 31;
      *(uint4*)(&As[r * 256 + (c16 ^ (r & 7)) * 8]) = v[it];
    }
  }
  f32x4 acc2[2][4] = {};
  __syncthreads();
  for (int nc = 0; nc < 4; ++nc) {
    // ---- gemm1 chunk: 64 rows x 64 h1-cols; wave owns 32x32 ----
    f32x4 acc1[2][2] = {};
#pragma unroll
    for (int kc = 0; kc < 256; kc += 32) {
      bf16x8 a[2], b[2];
#pragma unroll
      for (int i = 0; i < 2; ++i) {
        int row = wr * 32 + i * 16 + l15;
        a[i] = *(const bf16x8*)(&As[row * 256 + ((kc + quad * 8) ^ ((row & 7) << 3))]);
      }
#pragma unroll
      for (int i = 0; i < 2; ++i) {
        int ftile = (nc * 4 + wc * 2 + i) * 8 + (kc >> 5);
        b[i] = *(const bf16x8*)(W1t + ftile * 512 + lane * 8);
      }
#pragma unroll
      for (int mi = 0; mi < 2; ++mi)
#pragma unroll
        for (int ni = 0; ni < 2; ++ni)
          acc1[mi][ni] = __builtin_amdgcn_mfma_f32_16x16x32_bf16(a[mi], b[ni], acc1[mi][ni], 0, 0, 0);
    }
    __syncthreads();   // prev iter's gemm2 finished reading Hc
    // ---- GELU(acc1 + b1) -> Hc (bf16, swizzled) ----
#pragma unroll
    for (int mi = 0; mi < 2; ++mi)
#pragma unroll
      for (int ni = 0; ni < 2; ++ni) {
        int col = wc * 32 + ni * 16 + l15;
        float bv = b1[nc * 64 + col];
#pragma unroll
        for (int rr = 0; rr < 4; ++rr) {
          int row = wr * 32 + mi * 16 + quad * 4 + rr;
          Hc[row * 64 + (col ^ ((row & 7) << 3))] = f2bf(fast_gelu(acc1[mi][ni][rr] + bv));
        }
      }
    __syncthreads();
    // ---- gemm2 partial: acc2 += Hc(64x64) @ W2[:, nc*64 .. +64]; 32x64/wave
#pragma unroll
    for (int kc = 0; kc < 64; kc += 32) {
      bf16x8 a[2], b[4];
#pragma unroll
      for (int i = 0; i < 2; ++i) {
        int row = wr * 32 + i * 16 + l15;
        a[i] = *(const bf16x8*)(&Hc[row * 64 + ((kc + quad * 8) ^ ((row & 7) << 3))]);
      }
#pragma unroll
      for (int i = 0; i < 4; ++i) {
        int ftile = (wc * 4 + i) * 8 + nc * 2 + (kc >> 5);
        b[i] = *(const bf16x8*)(W2t + ftile * 512 + lane * 8);
      }
#pragma unroll
      for (int mi = 0; mi < 2; ++mi)
#pragma unroll
        for (int ni = 0; ni < 4; ++ni)
          acc2[mi][ni] = __builtin_amdgcn_mfma_f32_16x16x32_bf16(a[mi], b[ni], acc2[mi][ni], 0, 0, 0);
    }
  }
  // ---- epilogue: + b2 + resid, fp32 out ----
#pragma unroll
  for (int mi = 0; mi < 2; ++mi)
#pragma unroll
    for (int ni = 0; ni < 4; ++ni) {
      int col = wc * 64 + ni * 16 + l15;
      float bv = b2[col];
#pragma unroll
      for (int rr = 0; rr < 4; ++rr) {
        int row = m0 + wr * 32 + mi * 16 + quad * 4 + rr;
        if (row < M) {
          float v = acc2[mi][ni][rr] + bv + resid[(size_t)row * 128 + col];
          outp[(size_t)row * 128 + col] = v;
        }
      }
    }
}

extern "C" void kernel_launch(void* const* d_in, const int* in_sizes, int n_in,
                              void* d_out, int out_size, void* d_ws, size_t ws_size,
                              hipStream_t stream) {
  const float* x    = (const float*)d_in[0];
  const int* esrc   = (const int*)d_in[1];
  const int* edst   = (const int*)d_in[2];
  const float* sn_g = (const float*)d_in[4];
  const float* sn_b = (const float*)d_in[5];
  const float* nn_g = (const float*)d_in[6];
  const float* nn_b = (const float*)d_in[7];
  const float* W1   = (const float*)d_in[8];
  const float* b1   = (const float*)d_in[9];
  const float* W2   = (const float*)d_in[10];
  const float* b2   = (const float*)d_in[11];

  char* ws = (char*)d_ws;
  const size_t H_BYTES = (size_t)TOK * 256 * 2;          // 51.2 MB
  unsigned short* h = (unsigned short*)ws;               // [TOK][256] bf16
  // CSR + xb region (dead after gather):
  char* csr = ws + H_BYTES;
  int* cnt        = (int*)(csr);                          // 50000 ints
  int* part       = (int*)(csr + 200000);                 // 50000 ints
  int* rs         = (int*)(csr + 400000);                 // 50001 ints
  int* cursor     = (int*)(csr + 600016);                 // 50000 ints
  int* bsum       = (int*)(csr + 800016);                 // 49 ints
  int* boff       = (int*)(csr + 800224);                 // 64 ints
  int* sorted_src = (int*)(csr + 800512);                 // 800000 ints -> ends 4,000,512
  unsigned short* xb = (unsigned short*)(csr + 4194304);  // [N][2][128] bf16, 25.6 MB
  unsigned short* W1t = (unsigned short*)(ws + 2 * H_BYTES);
  unsigned short* W2t = W1t + 65536;

  hipMemsetAsync(cnt, 0, (size_t)N_ * sizeof(int), stream);
  prep_k<<<16009, 256, 0, stream>>>(x, W1, W2, edst, xb, W1t, W2t, cnt);
  scan1_k<<<49, 1024, 0, stream>>>(cnt, part, bsum);
  scan2_k<<<1, 64, 0, stream>>>(bsum, boff);
  scan3_k<<<49, 1024, 0, stream>>>(part, boff, rs, cursor);
  fill_k<<<(E_ + 255) / 256, 256, 0, stream>>>(esrc, edst, cursor, sorted_src);
  gather_ln_k<<<N_ / 4, 256, 0, stream>>>(xb, rs, sorted_src,
                                          sn_g, sn_b, nn_g, nn_b, h);
  fused_mlp_k<<<(TOK + 63) / 64, 256, 0, stream>>>(h, W1t, W2t, b1, b2,
                                                   x, (float*)d_out, TOK);
}